// Round 7
// baseline (913.447 us; speedup 1.0000x reference)
//
#include <hip/hip_runtime.h>

// ---------------------------------------------------------------------------
// S = D = 4096 single-head attention (with the module's v-transpose bug).
// All six 4096^3 matmuls are NT GEMMs: C[m,n] = sum_k A[m,k]B[n,k].
// Round 7: r6 schedule, MFMA shape 32x32x16 (2382 TF ubench vs 2075 for
// 16x16x32). LDS re-subtiled to [32][16] with granule-XOR swizzle
// (g ^= row&1), staged linear-dest + inverse-permuted global source.
// ---------------------------------------------------------------------------

typedef __attribute__((ext_vector_type(16))) float f32x16;
typedef __attribute__((ext_vector_type(8))) short short8;
typedef __attribute__((ext_vector_type(4))) unsigned short us4;

#define DIM 4096
#define NT  64   // K tiles of 64

__device__ __forceinline__ unsigned short f2bf(float f) {
    unsigned int u = __builtin_bit_cast(unsigned int, f);
    u += 0x7fffu + ((u >> 16) & 1u);   // round-to-nearest-even
    return (unsigned short)(u >> 16);
}

__device__ __forceinline__ void gll16(const void* g, void* l) {
    __builtin_amdgcn_global_load_lds(
        (const __attribute__((address_space(1))) unsigned int*)g,
        (__attribute__((address_space(3))) unsigned int*)l,
        16, 0, 0);
}

// ---------------------------------------------------------------------------
__global__ void cast_kernel(const float* __restrict__ in, unsigned short* __restrict__ out) {
    const size_t i = ((size_t)blockIdx.x * 256 + threadIdx.x) * 4;
    float4 x = *(const float4*)(in + i);
    us4 y;
    y.x = f2bf(x.x); y.y = f2bf(x.y); y.z = f2bf(x.z); y.w = f2bf(x.w);
    *(us4*)(out + i) = y;
}

// ---------------------------------------------------------------------------
// 256x256 NT GEMM, BK=64, 8 waves (2x4, wave tile 128x64), 128 KiB LDS dbuf.
// LDS: tile [256][64] as 8 R-groups x 4 K-groups of [32][16] subtiles (1KB).
// Within a subtile, 16B granule at position row*2+q holds k-half q^(row&1)
// (XOR spreads the column read across banks; bijective per subtile).
// Frag read (lane l): byte = subtile*1024 + (l&31)*32 + ((l>>5)^(l&1))*16.
// Per-tile schedule (identical to r6):
//   p0: read b0,alo (exposed); stage A(t+1)h1; Q00 (mf0-1 x nf0)
//   p1: read b1,ahi (hidden);  stage B(t+1)h0; Q01 (mf0-1 x nf1)
//   R1 barrier (all tile-t reads issued)
//   p2:                        stage B(t+1)h1; Q11 (mf2-3 x nf1)
//   p3:                        stage A(t+2)h0; Q10 (mf2-3 x nf0)
//   boundary: vmcnt(2)+barrier
// EPI: 0 = bf16 out (+opt bias), 1 = f32 out * 1/64, 2 = f32 out + bias + res
// ---------------------------------------------------------------------------
template <int EPI>
__global__ __launch_bounds__(512, 2)
void gemm256(const unsigned short* __restrict__ A, const unsigned short* __restrict__ B,
             void* __restrict__ Cout, const float* __restrict__ bias,
             const float* __restrict__ res) {
    __shared__ alignas(16) char lds[131072];

    const int tid = threadIdx.x;
    const int w = tid >> 6, l = tid & 63;
    const int wr = w >> 2, wc = w & 3;          // 2 x 4 waves, wave tile 128x64

    // bijective XCD swizzle (256 blocks, 8 XCDs)
    const int bid = blockIdx.x;
    const int swz = (bid & 7) * 32 + (bid >> 3);
    const int row0 = (swz >> 4) << 8;
    const int col0 = (swz & 15) << 8;

    // frag-read lane offset within a [32][16] subtile
    const int laneR = (l & 31) * 32 + (((l >> 5) ^ (l & 1)) << 4);
    // staging lane constants: lane l -> granule l: row l>>1, k-half (l&1)^((l>>1)&1)
    const int sg_row = l >> 1;
    const int sg_k   = ((l & 1) ^ ((l >> 1) & 1)) << 3;   // element offset

    f32x16 acc[4][2];
#pragma unroll
    for (int m = 0; m < 4; ++m)
#pragma unroll
        for (int n = 0; n < 2; ++n)
#pragma unroll
            for (int r = 0; r < 16; ++r) acc[m][n][r] = 0.f;

    char* const ldsp = (char*)lds;

    // stage half-tile h (R-groups h*4..h*4+3) of K-tile t; 2 gll16/thread.
    // wave w covers R = h*4 + (w&3), Kg = (w>>2)*2 + {0,1}.
    auto stage = [&](const unsigned short* __restrict__ M, char* ldsMat, int rowbase,
                     int t, int h) {
        const int R = h * 4 + (w & 3);
        const int grow = rowbase + R * 32 + sg_row;
        const int Kg0 = (w >> 2) * 2;
#pragma unroll
        for (int j = 0; j < 2; ++j) {
            const int Kg = Kg0 + j;
            gll16(M + (size_t)grow * DIM + t * 64 + Kg * 16 + sg_k,
                  ldsMat + ((R * 4 + Kg) << 10));
        }
    };

    // ---- prologue: tile0 (4 half-tiles) + A(1)h0; allow A(1)h0 in flight ----
    stage(A, ldsp,          row0, 0, 0);
    stage(A, ldsp,          row0, 0, 1);
    stage(B, ldsp + 32768,  col0, 0, 0);
    stage(B, ldsp + 32768,  col0, 0, 1);
    stage(A, ldsp + 65536,  row0, 1, 0);
    asm volatile("s_waitcnt vmcnt(2)\ns_barrier" ::: "memory");

#pragma unroll 1
    for (int t = 0; t < NT; ++t) {
        const char* Ab = ldsp + (t & 1) * 65536;
        const char* Bb = Ab + 32768;
        const int t1 = (t + 1 < NT) ? t + 1 : NT - 1;   // tail re-stages same bytes
        const int t2 = (t + 2 < NT) ? t + 2 : NT - 1;
        char* A1 = ldsp + (t1 & 1) * 65536;
        char* B1 = A1 + 32768;
        char* A2 = ldsp + (t2 & 1) * 65536;

        const int aoff = wr * 16384 + laneR;   // + mf*4096 + ks*1024
        const int boff = wc * 8192 + laneR;    // + nf*4096 + ks*1024

        short8 alo[2][4], ahi[2][4], b0[4], b1[4];

        // ====== p0 : read b0, alo; stage A(t+1)h1; Q00 ======
#pragma unroll
        for (int ks = 0; ks < 4; ++ks)
            b0[ks] = *(const short8*)(Bb + boff + (ks << 10));
#pragma unroll
        for (int mf = 0; mf < 2; ++mf)
#pragma unroll
            for (int ks = 0; ks < 4; ++ks)
                alo[mf][ks] = *(const short8*)(Ab + aoff + (mf << 12) + (ks << 10));
        stage(A, A1, row0, t1, 1);
        __builtin_amdgcn_s_setprio(1);
#pragma unroll
        for (int mf = 0; mf < 2; ++mf)
#pragma unroll
            for (int ks = 0; ks < 4; ++ks)
                acc[mf][0] = __builtin_amdgcn_mfma_f32_32x32x16_bf16(
                    alo[mf][ks], b0[ks], acc[mf][0], 0, 0, 0);
        __builtin_amdgcn_s_setprio(0);

        // ====== p1 : read b1, ahi (hidden); stage B(t+1)h0; Q01 ======
#pragma unroll
        for (int ks = 0; ks < 4; ++ks)
            b1[ks] = *(const short8*)(Bb + boff + 4096 + (ks << 10));
#pragma unroll
        for (int mf = 0; mf < 2; ++mf)
#pragma unroll
            for (int ks = 0; ks < 4; ++ks)
                ahi[mf][ks] = *(const short8*)(Ab + aoff + ((2 + mf) << 12) + (ks << 10));
        stage(B, B1, col0, t1, 0);
        __builtin_amdgcn_s_setprio(1);
#pragma unroll
        for (int mf = 0; mf < 2; ++mf)
#pragma unroll
            for (int ks = 0; ks < 4; ++ks)
                acc[mf][1] = __builtin_amdgcn_mfma_f32_32x32x16_bf16(
                    alo[mf][ks], b1[ks], acc[mf][1], 0, 0, 0);
        __builtin_amdgcn_s_setprio(0);

        // R1: all tile-t LDS reads issued (alo fully consumed); after this it
        // is safe for p3 to stage A(t+2)h0 into the alo region.
        asm volatile("s_barrier" ::: "memory");

        // ====== p2 : stage B(t+1)h1; Q11 (all-register) ======
        stage(B, B1, col0, t1, 1);
        __builtin_amdgcn_s_setprio(1);
#pragma unroll
        for (int mf = 0; mf < 2; ++mf)
#pragma unroll
            for (int ks = 0; ks < 4; ++ks)
                acc[2 + mf][1] = __builtin_amdgcn_mfma_f32_32x32x16_bf16(
                    ahi[mf][ks], b1[ks], acc[2 + mf][1], 0, 0, 0);
        __builtin_amdgcn_s_setprio(0);

        // ====== p3 : stage A(t+2)h0; Q10 (all-register); boundary ======
        stage(A, A2, row0, t2, 0);
        __builtin_amdgcn_s_setprio(1);
#pragma unroll
        for (int mf = 0; mf < 2; ++mf)
#pragma unroll
            for (int ks = 0; ks < 4; ++ks)
                acc[2 + mf][0] = __builtin_amdgcn_mfma_f32_32x32x16_bf16(
                    ahi[mf][ks], b0[ks], acc[2 + mf][0], 0, 0, 0);
        __builtin_amdgcn_s_setprio(0);
        // tile boundary: tile t+1 fully landed; only A(t+2)h0 (2 newest) in flight.
        asm volatile("s_waitcnt vmcnt(2)\ns_barrier" ::: "memory");
    }
    asm volatile("s_waitcnt vmcnt(0)" ::: "memory");

    // ---- epilogue: D col = lane&31, row = (reg&3) + 8*(reg>>2) + 4*(lane>>5) ----
#pragma unroll
    for (int mf = 0; mf < 4; ++mf) {
        const int grow_b = row0 + wr * 128 + mf * 32 + ((l >> 5) << 2);
#pragma unroll
        for (int nf = 0; nf < 2; ++nf) {
            const int gcol = col0 + wc * 64 + nf * 32 + (l & 31);
            float bias_v = 0.f;
            if constexpr (EPI != 1) {
                if (bias) bias_v = bias[gcol];
            }
#pragma unroll
            for (int rg = 0; rg < 16; ++rg) {
                const int grow = grow_b + (rg & 3) + ((rg >> 2) << 3);
                const size_t idx = (size_t)grow * DIM + gcol;
                const float x = acc[mf][nf][rg] + bias_v;
                if constexpr (EPI == 0) {
                    ((unsigned short*)Cout)[idx] = f2bf(x);
                } else if constexpr (EPI == 1) {
                    ((float*)Cout)[idx] = x * 0.015625f;   // 1/64
                } else {
                    ((float*)Cout)[idx] = x + res[idx];
                }
            }
        }
    }
}

// ---------------------------------------------------------------------------
__global__ __launch_bounds__(256)
void softmax_kernel(const float* __restrict__ S, unsigned short* __restrict__ P) {
    const int row = blockIdx.x;
    const int t = threadIdx.x;
    const float* src = S + (size_t)row * DIM;

    float v[16];
#pragma unroll
    for (int i = 0; i < 16; ++i) v[i] = src[t + (i << 8)];

    float m = v[0];
#pragma unroll
    for (int i = 1; i < 16; ++i) m = fmaxf(m, v[i]);
#pragma unroll
    for (int off = 32; off > 0; off >>= 1) m = fmaxf(m, __shfl_xor(m, off));

    __shared__ float redm[4], reds[4];
    if ((t & 63) == 0) redm[t >> 6] = m;
    __syncthreads();
    m = fmaxf(fmaxf(redm[0], redm[1]), fmaxf(redm[2], redm[3]));

    float s = 0.f;
#pragma unroll
    for (int i = 0; i < 16; ++i) {
        v[i] = expf(v[i] - m);
        s += v[i];
    }
#pragma unroll
    for (int off = 32; off > 0; off >>= 1) s += __shfl_xor(s, off);
    if ((t & 63) == 0) reds[t >> 6] = s;
    __syncthreads();
    s = (reds[0] + reds[1]) + (reds[2] + reds[3]);

    const float inv = 1.0f / s;
    unsigned short* dst = P + (size_t)row * DIM;
#pragma unroll
    for (int i = 0; i < 16; ++i) dst[t + (i << 8)] = f2bf(v[i] * inv);
}

// ---------------------------------------------------------------------------
extern "C" void kernel_launch(void* const* d_in, const int* in_sizes, int n_in,
                              void* d_out, int out_size, void* d_ws, size_t ws_size,
                              hipStream_t stream) {
    const float* query = (const float*)d_in[0];
    const float* key   = (const float*)d_in[1];
    const float* value = (const float*)d_in[2];
    const float* Wq    = (const float*)d_in[3];
    const float* bq    = (const float*)d_in[4];
    const float* Wk    = (const float*)d_in[5];
    const float* bk    = (const float*)d_in[6];
    const float* Wv    = (const float*)d_in[7];
    const float* bv    = (const float*)d_in[8];
    const float* Wo    = (const float*)d_in[9];
    const float* bo    = (const float*)d_in[10];

    const size_t SZ = (size_t)DIM * DIM;
    unsigned short* qb   = (unsigned short*)d_ws;
    unsigned short* kb   = qb + SZ;
    unsigned short* vb   = kb + SZ;
    unsigned short* xb   = vb + SZ;          // reused cast buffer (inputs)
    unsigned short* wb   = xb + SZ;          // reused cast buffer (weights)
    unsigned short* Pb   = wb + SZ;
    unsigned short* ctxb = Pb + SZ;
    float* scores = (float*)(ctxb + SZ);     // 4*SZ bytes

    const dim3 cg(16384), cb(256);
    const dim3 gg(256), gb(512);

    // q = query @ Wq.T + bq
    cast_kernel<<<cg, cb, 0, stream>>>(query, xb);
    cast_kernel<<<cg, cb, 0, stream>>>(Wq, wb);
    gemm256<0><<<gg, gb, 0, stream>>>(xb, wb, qb, bq, nullptr);
    // k = key @ Wk.T + bk
    cast_kernel<<<cg, cb, 0, stream>>>(key, xb);
    cast_kernel<<<cg, cb, 0, stream>>>(Wk, wb);
    gemm256<0><<<gg, gb, 0, stream>>>(xb, wb, kb, bk, nullptr);
    // v = value @ Wv.T + bv
    cast_kernel<<<cg, cb, 0, stream>>>(value, xb);
    cast_kernel<<<cg, cb, 0, stream>>>(Wv, wb);
    gemm256<0><<<gg, gb, 0, stream>>>(xb, wb, vb, bv, nullptr);
    // scores = q @ k.T / 64   (fp32)
    gemm256<1><<<gg, gb, 0, stream>>>(qb, kb, scores, nullptr, nullptr);
    // P = softmax(scores)  (bf16)
    softmax_kernel<<<4096, 256, 0, stream>>>(scores, Pb);
    // ctx = P @ v.T  (the v-transpose bug makes this NT too)
    gemm256<0><<<gg, gb, 0, stream>>>(Pb, vb, ctxb, nullptr, nullptr);
    // out = ctx @ Wo.T + bo + value   (fp32)
    cast_kernel<<<cg, cb, 0, stream>>>(Wo, wb);
    gemm256<2><<<gg, gb, 0, stream>>>(ctxb, wb, d_out, bo, value);
}

// Round 8
// 806.513 us; speedup vs baseline: 1.1326x; 1.1326x over previous
//
#include <hip/hip_runtime.h>

// ---------------------------------------------------------------------------
// S = D = 4096 single-head attention (with the module's v-transpose bug).
// All six 4096^3 matmuls are NT GEMMs: C[m,n] = sum_k A[m,k]B[n,k].
// Round 8: 16x16x32 + st_16x32 swizzle (conflict-free, r6 layout) with a
// fully rotated schedule: every ds_read is >=1 phase ahead of its consumer.
//   P0: read b1,ahi(t);   MFMA Q00(alo,b0);  R1 barrier
//   P1: stage A(t+2)h0+h1; MFMA Q01(alo,b1)
//   P2: stage B(t+2)h0;    MFMA Q11(ahi,b1); publish vmcnt(6)+barrier
//   P3: read alo,b0(t+1);  stage B(t+2)h1;   MFMA Q10(ahi,b0)
// ---------------------------------------------------------------------------

typedef __attribute__((ext_vector_type(4))) float f32x4;
typedef __attribute__((ext_vector_type(8))) short short8;
typedef __attribute__((ext_vector_type(4))) unsigned short us4;

#define DIM 4096
#define NT  64   // K tiles of 64

__device__ __forceinline__ unsigned short f2bf(float f) {
    unsigned int u = __builtin_bit_cast(unsigned int, f);
    u += 0x7fffu + ((u >> 16) & 1u);   // round-to-nearest-even
    return (unsigned short)(u >> 16);
}

__device__ __forceinline__ void gll16(const void* g, void* l) {
    __builtin_amdgcn_global_load_lds(
        (const __attribute__((address_space(1))) unsigned int*)g,
        (__attribute__((address_space(3))) unsigned int*)l,
        16, 0, 0);
}

// ---------------------------------------------------------------------------
__global__ void cast_kernel(const float* __restrict__ in, unsigned short* __restrict__ out) {
    const size_t i = ((size_t)blockIdx.x * 256 + threadIdx.x) * 4;
    float4 x = *(const float4*)(in + i);
    us4 y;
    y.x = f2bf(x.x); y.y = f2bf(x.y); y.z = f2bf(x.z); y.w = f2bf(x.w);
    *(us4*)(out + i) = y;
}

// ---------------------------------------------------------------------------
// 256x256 NT GEMM, BK=64, 8 waves (2x4, wave tile 128x64), 128 KiB LDS dbuf,
// st_16x32 swizzle via pre-swizzled global source (r6-verified layout).
// Schedule per K-tile t (buf p = t&1); see file header. Invariants at P0(t):
//   - alo(t), b0(t) in registers (read at P3(t-1) / prologue)
//   - buf(t) published; tile t+1 units in flight or landed
// WAR audit: A(t+2) staged P1(t) -> A(t) reads done by R1 (alo@P3(t-1),
// ahi@P0(t)); B(t+2)h0 staged P2(t) -> b0(t) read @P3(t-1); B(t+2)h1 staged
// P3(t) -> b1(t) read @P0(t). All separated by R1.
// Publish vmcnt(6): in-flight = A(t+2)x4 + B(t+2)h0 x2; drains B(t+1)h1
// (staged P3(t-1), 3 phases of flight).
// EPI: 0 = bf16 out (+opt bias), 1 = f32 out * 1/64, 2 = f32 out + bias + res
// ---------------------------------------------------------------------------
template <int EPI>
__global__ __launch_bounds__(512, 2)
void gemm256(const unsigned short* __restrict__ A, const unsigned short* __restrict__ B,
             void* __restrict__ Cout, const float* __restrict__ bias,
             const float* __restrict__ res) {
    __shared__ alignas(16) char lds[131072];

    const int tid = threadIdx.x;
    const int w = tid >> 6, l = tid & 63;
    const int wr = w >> 2, wc = w & 3;          // 2 x 4 waves, wave tile 128x64

    // bijective XCD swizzle (256 blocks, 8 XCDs)
    const int bid = blockIdx.x;
    const int swz = (bid & 7) * 32 + (bid >> 3);
    const int row0 = (swz >> 4) << 8;
    const int col0 = (swz & 15) << 8;

    // lane constants (r6-verified st_16x32 layout)
    const int laneA  = (l & 15) * 64 + (((l >> 4) << 4) ^ ((l & 8) << 2)); // swizzled frag-read byte
    const int sl_row = l >> 2;                                  // staging row within subtile
    const int sl_col = ((l & 3) << 3) ^ ((l & 32) ? 16 : 0);    // staging col elem (inverse swz)

    f32x4 acc[8][4];
    const f32x4 zero = {0.f, 0.f, 0.f, 0.f};
#pragma unroll
    for (int m = 0; m < 8; ++m)
#pragma unroll
        for (int n = 0; n < 4; ++n) acc[m][n] = zero;

    char* const ldsp = (char*)lds;
    char* const A0 = ldsp;
    char* const B0 = ldsp + 32768;
    char* const A1 = ldsp + 65536;
    char* const B1 = ldsp + 98304;

    const int aoff = wr * 16384 + laneA;
    const int boff = wc * 8192 + laneA;

    // stage half-tile h of K-tile t into ldsMat: 2 gll16/thread (16 chunks/8 waves)
    auto stage = [&](const unsigned short* __restrict__ M, char* ldsMat, int rowbase,
                     int t, int h) {
        {
            const int rg = h * 8 + (w >> 1), cg = w & 1;
            gll16(M + (size_t)(rowbase + rg * 16 + sl_row) * DIM + t * 64 + cg * 32 + sl_col,
                  ldsMat + ((rg * 2 + cg) << 10));
        }
        {
            const int s = 8 + w;
            const int rg = h * 8 + (s >> 1), cg = s & 1;
            gll16(M + (size_t)(rowbase + rg * 16 + sl_row) * DIM + t * 64 + cg * 32 + sl_col,
                  ldsMat + ((rg * 2 + cg) << 10));
        }
    };

    short8 alo[4][2], ahi[4][2], b1[2][2], b0A[2][2], b0B[2][2];

    // ---- prologue: stage tiles 0 and 1 fully; publish tile 0; pre-read alo,b0 ----
    stage(A, A0, row0, 0, 0); stage(A, A0, row0, 0, 1);
    stage(B, B0, col0, 0, 0); stage(B, B0, col0, 0, 1);
    stage(A, A1, row0, 1, 0); stage(A, A1, row0, 1, 1);
    stage(B, B1, col0, 1, 0); stage(B, B1, col0, 1, 1);
    asm volatile("s_waitcnt vmcnt(8)\ns_barrier" ::: "memory");   // tile0 landed
#pragma unroll
    for (int m2 = 0; m2 < 4; ++m2)
#pragma unroll
        for (int ks = 0; ks < 2; ++ks)
            alo[m2][ks] = *(const short8*)(A0 + aoff + ((m2 * 2 + ks) << 10));
#pragma unroll
    for (int n2 = 0; n2 < 2; ++n2)
#pragma unroll
        for (int ks = 0; ks < 2; ++ks)
            b0A[n2][ks] = *(const short8*)(B0 + boff + ((n2 * 2 + ks) << 10));

    // one K-tile; Abuf/Bbuf = buf(t) (read + t+2 staging target); An/Bn = buf(t+1)
    auto body = [&](int t, char* Abuf, char* Bbuf, const char* An, const char* Bn,
                    short8 (&b0c)[2][2], short8 (&b0n)[2][2]) {
        const int t2 = (t + 2 < NT) ? t + 2 : NT - 1;   // tail re-stages same bytes

        // ---- P0: read b1(t), ahi(t) (for P1/P2/P3); MFMA Q00(alo,b0c); R1 ----
#pragma unroll
        for (int n2 = 0; n2 < 2; ++n2)
#pragma unroll
            for (int ks = 0; ks < 2; ++ks)
                b1[n2][ks] = *(const short8*)(Bbuf + boff + (((2 + n2) * 2 + ks) << 10));
#pragma unroll
        for (int m2 = 0; m2 < 4; ++m2)
#pragma unroll
            for (int ks = 0; ks < 2; ++ks)
                ahi[m2][ks] = *(const short8*)(Abuf + aoff + (((4 + m2) * 2 + ks) << 10));
        __builtin_amdgcn_s_setprio(1);
#pragma unroll
        for (int m2 = 0; m2 < 4; ++m2)
#pragma unroll
            for (int n2 = 0; n2 < 2; ++n2)
#pragma unroll
                for (int ks = 0; ks < 2; ++ks)
                    acc[m2][n2] = __builtin_amdgcn_mfma_f32_16x16x32_bf16(
                        alo[m2][ks], b0c[n2][ks], acc[m2][n2], 0, 0, 0);
        __builtin_amdgcn_s_setprio(0);
        // R1: all tile-t reads issued -> t+2 staging may overwrite buf(t)
        asm volatile("s_barrier" ::: "memory");

        // ---- P1: stage A(t+2) h0+h1; MFMA Q01(alo,b1) ----
        stage(A, Abuf, row0, t2, 0);
        stage(A, Abuf, row0, t2, 1);
        __builtin_amdgcn_s_setprio(1);
#pragma unroll
        for (int m2 = 0; m2 < 4; ++m2)
#pragma unroll
            for (int n2 = 0; n2 < 2; ++n2)
#pragma unroll
                for (int ks = 0; ks < 2; ++ks)
                    acc[m2][2 + n2] = __builtin_amdgcn_mfma_f32_16x16x32_bf16(
                        alo[m2][ks], b1[n2][ks], acc[m2][2 + n2], 0, 0, 0);
        __builtin_amdgcn_s_setprio(0);

        // ---- P2: stage B(t+2) h0; MFMA Q11(ahi,b1); publish t+1 ----
        stage(B, Bbuf, col0, t2, 0);
        __builtin_amdgcn_s_setprio(1);
#pragma unroll
        for (int m2 = 0; m2 < 4; ++m2)
#pragma unroll
            for (int n2 = 0; n2 < 2; ++n2)
#pragma unroll
                for (int ks = 0; ks < 2; ++ks)
                    acc[4 + m2][2 + n2] = __builtin_amdgcn_mfma_f32_16x16x32_bf16(
                        ahi[m2][ks], b1[n2][ks], acc[4 + m2][2 + n2], 0, 0, 0);
        __builtin_amdgcn_s_setprio(0);
        // publish: tile t+1 fully landed; 6 newest (A(t+2)x4, B(t+2)h0 x2) fly
        asm volatile("s_waitcnt vmcnt(6)\ns_barrier" ::: "memory");

        // ---- P3: read alo,b0 of t+1; stage B(t+2)h1; MFMA Q10(ahi,b0c) ----
#pragma unroll
        for (int m2 = 0; m2 < 4; ++m2)
#pragma unroll
            for (int ks = 0; ks < 2; ++ks)
                alo[m2][ks] = *(const short8*)(An + aoff + ((m2 * 2 + ks) << 10));
#pragma unroll
        for (int n2 = 0; n2 < 2; ++n2)
#pragma unroll
            for (int ks = 0; ks < 2; ++ks)
                b0n[n2][ks] = *(const short8*)(Bn + boff + ((n2 * 2 + ks) << 10));
        stage(B, Bbuf, col0, t2, 1);
        __builtin_amdgcn_s_setprio(1);
#pragma unroll
        for (int m2 = 0; m2 < 4; ++m2)
#pragma unroll
            for (int n2 = 0; n2 < 2; ++n2)
#pragma unroll
                for (int ks = 0; ks < 2; ++ks)
                    acc[4 + m2][n2] = __builtin_amdgcn_mfma_f32_16x16x32_bf16(
                        ahi[m2][ks], b0c[n2][ks], acc[4 + m2][n2], 0, 0, 0);
        __builtin_amdgcn_s_setprio(0);
    };

#pragma unroll 1
    for (int tt = 0; tt < NT / 2; ++tt) {
        const int t = 2 * tt;
        body(t,     A0, B0, A1, B1, b0A, b0B);
        body(t + 1, A1, B1, A0, B0, b0B, b0A);
    }
    asm volatile("s_waitcnt vmcnt(0)" ::: "memory");

    // ---- epilogue: D col = lane&15, row = (lane>>4)*4 + r ----
#pragma unroll
    for (int mf = 0; mf < 8; ++mf) {
        const int grow0 = row0 + wr * 128 + mf * 16 + ((l >> 4) << 2);
#pragma unroll
        for (int nf = 0; nf < 4; ++nf) {
            const int gcol = col0 + wc * 64 + nf * 16 + (l & 15);
            float bias_v = 0.f;
            if constexpr (EPI != 1) {
                if (bias) bias_v = bias[gcol];
            }
#pragma unroll
            for (int r = 0; r < 4; ++r) {
                const size_t idx = (size_t)(grow0 + r) * DIM + gcol;
                const float x = acc[mf][nf][r] + bias_v;
                if constexpr (EPI == 0) {
                    ((unsigned short*)Cout)[idx] = f2bf(x);
                } else if constexpr (EPI == 1) {
                    ((float*)Cout)[idx] = x * 0.015625f;   // 1/64
                } else {
                    ((float*)Cout)[idx] = x + res[idx];
                }
            }
        }
    }
}

// ---------------------------------------------------------------------------
__global__ __launch_bounds__(256)
void softmax_kernel(const float* __restrict__ S, unsigned short* __restrict__ P) {
    const int row = blockIdx.x;
    const int t = threadIdx.x;
    const float* src = S + (size_t)row * DIM;

    float v[16];
#pragma unroll
    for (int i = 0; i < 16; ++i) v[i] = src[t + (i << 8)];

    float m = v[0];
#pragma unroll
    for (int i = 1; i < 16; ++i) m = fmaxf(m, v[i]);
#pragma unroll
    for (int off = 32; off > 0; off >>= 1) m = fmaxf(m, __shfl_xor(m, off));

    __shared__ float redm[4], reds[4];
    if ((t & 63) == 0) redm[t >> 6] = m;
    __syncthreads();
    m = fmaxf(fmaxf(redm[0], redm[1]), fmaxf(redm[2], redm[3]));

    float s = 0.f;
#pragma unroll
    for (int i = 0; i < 16; ++i) {
        v[i] = expf(v[i] - m);
        s += v[i];
    }
#pragma unroll
    for (int off = 32; off > 0; off >>= 1) s += __shfl_xor(s, off);
    if ((t & 63) == 0) reds[t >> 6] = s;
    __syncthreads();
    s = (reds[0] + reds[1]) + (reds[2] + reds[3]);

    const float inv = 1.0f / s;
    unsigned short* dst = P + (size_t)row * DIM;
#pragma unroll
    for (int i = 0; i < 16; ++i) dst[t + (i << 8)] = f2bf(v[i] * inv);
}

// ---------------------------------------------------------------------------
extern "C" void kernel_launch(void* const* d_in, const int* in_sizes, int n_in,
                              void* d_out, int out_size, void* d_ws, size_t ws_size,
                              hipStream_t stream) {
    const float* query = (const float*)d_in[0];
    const float* key   = (const float*)d_in[1];
    const float* value = (const float*)d_in[2];
    const float* Wq    = (const float*)d_in[3];
    const float* bq    = (const float*)d_in[4];
    const float* Wk    = (const float*)d_in[5];
    const float* bk    = (const float*)d_in[6];
    const float* Wv    = (const float*)d_in[7];
    const float* bv    = (const float*)d_in[8];
    const float* Wo    = (const float*)d_in[9];
    const float* bo    = (const float*)d_in[10];

    const size_t SZ = (size_t)DIM * DIM;
    unsigned short* qb   = (unsigned short*)d_ws;
    unsigned short* kb   = qb + SZ;
    unsigned short* vb   = kb + SZ;
    unsigned short* xb   = vb + SZ;          // reused cast buffer (inputs)
    unsigned short* wb   = xb + SZ;          // reused cast buffer (weights)
    unsigned short* Pb   = wb + SZ;
    unsigned short* ctxb = Pb + SZ;
    float* scores = (float*)(ctxb + SZ);     // 4*SZ bytes

    const dim3 cg(16384), cb(256);
    const dim3 gg(256), gb(512);

    // q = query @ Wq.T + bq
    cast_kernel<<<cg, cb, 0, stream>>>(query, xb);
    cast_kernel<<<cg, cb, 0, stream>>>(Wq, wb);
    gemm256<0><<<gg, gb, 0, stream>>>(xb, wb, qb, bq, nullptr);
    // k = key @ Wk.T + bk
    cast_kernel<<<cg, cb, 0, stream>>>(key, xb);
    cast_kernel<<<cg, cb, 0, stream>>>(Wk, wb);
    gemm256<0><<<gg, gb, 0, stream>>>(xb, wb, kb, bk, nullptr);
    // v = value @ Wv.T + bv
    cast_kernel<<<cg, cb, 0, stream>>>(value, xb);
    cast_kernel<<<cg, cb, 0, stream>>>(Wv, wb);
    gemm256<0><<<gg, gb, 0, stream>>>(xb, wb, vb, bv, nullptr);
    // scores = q @ k.T / 64   (fp32)
    gemm256<1><<<gg, gb, 0, stream>>>(qb, kb, scores, nullptr, nullptr);
    // P = softmax(scores)  (bf16)
    softmax_kernel<<<4096, 256, 0, stream>>>(scores, Pb);
    // ctx = P @ v.T  (the v-transpose bug makes this NT too)
    gemm256<0><<<gg, gb, 0, stream>>>(Pb, vb, ctxb, nullptr, nullptr);
    // out = ctx @ Wo.T + bo + value   (fp32)
    cast_kernel<<<cg, cb, 0, stream>>>(Wo, wb);
    gemm256<2><<<gg, gb, 0, stream>>>(ctxb, wb, d_out, bo, value);
}

// Round 10
// 793.139 us; speedup vs baseline: 1.1517x; 1.0169x over previous
//
#include <hip/hip_runtime.h>

// ---------------------------------------------------------------------------
// S = D = 4096 single-head attention (with the module's v-transpose bug).
// All six 4096^3 matmuls are NT GEMMs: C[m,n] = sum_k A[m,k]B[n,k].
// Round 10: round 9 fused-softmax pipeline with the residual wiring fixed:
// the residual is the RAW value input (bf16 cast in xb), NOT the projected v.
//   scores GEMM writes E = exp(logits/64) bf16 (no max-sub; max logit ~9)
//   rowsum kernel computes invs[row] = 1/sum(E[row])
//   PV GEMM epilogue scales by invs[row]  (softmax factorizes out of PV)
//   final GEMM residual read from bf16 xb (= cast of raw value)
// ---------------------------------------------------------------------------

typedef __attribute__((ext_vector_type(4))) float f32x4;
typedef __attribute__((ext_vector_type(8))) short short8;
typedef __attribute__((ext_vector_type(4))) unsigned short us4;

#define DIM 4096
#define NT  64   // K tiles of 64

__device__ __forceinline__ unsigned short f2bf(float f) {
    unsigned int u = __builtin_bit_cast(unsigned int, f);
    u += 0x7fffu + ((u >> 16) & 1u);   // round-to-nearest-even
    return (unsigned short)(u >> 16);
}

__device__ __forceinline__ float bf2f(unsigned short h) {
    return __builtin_bit_cast(float, (unsigned int)h << 16);
}

__device__ __forceinline__ void gll16(const void* g, void* l) {
    __builtin_amdgcn_global_load_lds(
        (const __attribute__((address_space(1))) unsigned int*)g,
        (__attribute__((address_space(3))) unsigned int*)l,
        16, 0, 0);
}

// ---------------------------------------------------------------------------
__global__ void cast_kernel(const float* __restrict__ in, unsigned short* __restrict__ out) {
    const size_t i = ((size_t)blockIdx.x * 256 + threadIdx.x) * 4;
    float4 x = *(const float4*)(in + i);
    us4 y;
    y.x = f2bf(x.x); y.y = f2bf(x.y); y.z = f2bf(x.z); y.w = f2bf(x.w);
    *(us4*)(out + i) = y;
}

// ---------------------------------------------------------------------------
// 256x256 NT GEMM, BK=64, 8 waves (2x4, wave tile 128x64), 128 KiB LDS dbuf,
// st_16x32 swizzle via pre-swizzled global source (r6-verified layout).
// Loop schedule identical to round 8 (best measured):
//   P0: read b1,ahi(t);    MFMA Q00(alo,b0);  R1 barrier
//   P1: stage A(t+2)h0+h1; MFMA Q01(alo,b1)
//   P2: stage B(t+2)h0;    MFMA Q11(ahi,b1);  publish vmcnt(6)+barrier
//   P3: read alo,b0(t+1);  stage B(t+2)h1;    MFMA Q10(ahi,b0)
// EPI: 0 = bf16 out + bias            (projections)
//      1 = bf16 out exp(acc/64)       (E for softmax)
//      2 = f32 out + bias + bf16 res  (final; res = bf16 cast of raw value)
//      3 = bf16 out * rowscale[row]   (PV with softmax normalization)
// ---------------------------------------------------------------------------
template <int EPI>
__global__ __launch_bounds__(512, 2)
void gemm256(const unsigned short* __restrict__ A, const unsigned short* __restrict__ B,
             void* __restrict__ Cout, const float* __restrict__ bias,
             const unsigned short* __restrict__ resb, const float* __restrict__ rowscale) {
    __shared__ alignas(16) char lds[131072];

    const int tid = threadIdx.x;
    const int w = tid >> 6, l = tid & 63;
    const int wr = w >> 2, wc = w & 3;          // 2 x 4 waves, wave tile 128x64

    // bijective XCD swizzle (256 blocks, 8 XCDs)
    const int bid = blockIdx.x;
    const int swz = (bid & 7) * 32 + (bid >> 3);
    const int row0 = (swz >> 4) << 8;
    const int col0 = (swz & 15) << 8;

    // lane constants (st_16x32 layout)
    const int laneA  = (l & 15) * 64 + (((l >> 4) << 4) ^ ((l & 8) << 2)); // swizzled frag-read byte
    const int sl_row = l >> 2;                                  // staging row within subtile
    const int sl_col = ((l & 3) << 3) ^ ((l & 32) ? 16 : 0);    // staging col elem (inverse swz)

    f32x4 acc[8][4];
    const f32x4 zero = {0.f, 0.f, 0.f, 0.f};
#pragma unroll
    for (int m = 0; m < 8; ++m)
#pragma unroll
        for (int n = 0; n < 4; ++n) acc[m][n] = zero;

    char* const ldsp = (char*)lds;
    char* const A0 = ldsp;
    char* const B0 = ldsp + 32768;
    char* const A1 = ldsp + 65536;
    char* const B1 = ldsp + 98304;

    const int aoff = wr * 16384 + laneA;
    const int boff = wc * 8192 + laneA;

    // stage half-tile h of K-tile t into ldsMat: 2 gll16/thread (16 chunks/8 waves)
    auto stage = [&](const unsigned short* __restrict__ M, char* ldsMat, int rowbase,
                     int t, int h) {
        {
            const int rg = h * 8 + (w >> 1), cg = w & 1;
            gll16(M + (size_t)(rowbase + rg * 16 + sl_row) * DIM + t * 64 + cg * 32 + sl_col,
                  ldsMat + ((rg * 2 + cg) << 10));
        }
        {
            const int s = 8 + w;
            const int rg = h * 8 + (s >> 1), cg = s & 1;
            gll16(M + (size_t)(rowbase + rg * 16 + sl_row) * DIM + t * 64 + cg * 32 + sl_col,
                  ldsMat + ((rg * 2 + cg) << 10));
        }
    };

    short8 alo[4][2], ahi[4][2], b1[2][2], b0A[2][2], b0B[2][2];

    // ---- prologue: stage tiles 0 and 1 fully; publish tile 0; pre-read alo,b0 ----
    stage(A, A0, row0, 0, 0); stage(A, A0, row0, 0, 1);
    stage(B, B0, col0, 0, 0); stage(B, B0, col0, 0, 1);
    stage(A, A1, row0, 1, 0); stage(A, A1, row0, 1, 1);
    stage(B, B1, col0, 1, 0); stage(B, B1, col0, 1, 1);
    asm volatile("s_waitcnt vmcnt(8)\ns_barrier" ::: "memory");   // tile0 landed
#pragma unroll
    for (int m2 = 0; m2 < 4; ++m2)
#pragma unroll
        for (int ks = 0; ks < 2; ++ks)
            alo[m2][ks] = *(const short8*)(A0 + aoff + ((m2 * 2 + ks) << 10));
#pragma unroll
    for (int n2 = 0; n2 < 2; ++n2)
#pragma unroll
        for (int ks = 0; ks < 2; ++ks)
            b0A[n2][ks] = *(const short8*)(B0 + boff + ((n2 * 2 + ks) << 10));

    // one K-tile; Abuf/Bbuf = buf(t) (read + t+2 staging target); An/Bn = buf(t+1)
    auto body = [&](int t, char* Abuf, char* Bbuf, const char* An, const char* Bn,
                    short8 (&b0c)[2][2], short8 (&b0n)[2][2]) {
        const int t2 = (t + 2 < NT) ? t + 2 : NT - 1;   // tail re-stages same bytes

        // ---- P0: read b1(t), ahi(t); MFMA Q00(alo,b0c); R1 ----
#pragma unroll
        for (int n2 = 0; n2 < 2; ++n2)
#pragma unroll
            for (int ks = 0; ks < 2; ++ks)
                b1[n2][ks] = *(const short8*)(Bbuf + boff + (((2 + n2) * 2 + ks) << 10));
#pragma unroll
        for (int m2 = 0; m2 < 4; ++m2)
#pragma unroll
            for (int ks = 0; ks < 2; ++ks)
                ahi[m2][ks] = *(const short8*)(Abuf + aoff + (((4 + m2) * 2 + ks) << 10));
        __builtin_amdgcn_s_setprio(1);
#pragma unroll
        for (int m2 = 0; m2 < 4; ++m2)
#pragma unroll
            for (int n2 = 0; n2 < 2; ++n2)
#pragma unroll
                for (int ks = 0; ks < 2; ++ks)
                    acc[m2][n2] = __builtin_amdgcn_mfma_f32_16x16x32_bf16(
                        alo[m2][ks], b0c[n2][ks], acc[m2][n2], 0, 0, 0);
        __builtin_amdgcn_s_setprio(0);
        // R1: all tile-t reads issued -> t+2 staging may overwrite buf(t)
        asm volatile("s_barrier" ::: "memory");

        // ---- P1: stage A(t+2) h0+h1; MFMA Q01(alo,b1) ----
        stage(A, Abuf, row0, t2, 0);
        stage(A, Abuf, row0, t2, 1);
        __builtin_amdgcn_s_setprio(1);
#pragma unroll
        for (int m2 = 0; m2 < 4; ++m2)
#pragma unroll
            for (int n2 = 0; n2 < 2; ++n2)
#pragma unroll
                for (int ks = 0; ks < 2; ++ks)
                    acc[m2][2 + n2] = __builtin_amdgcn_mfma_f32_16x16x32_bf16(
                        alo[m2][ks], b1[n2][ks], acc[m2][2 + n2], 0, 0, 0);
        __builtin_amdgcn_s_setprio(0);

        // ---- P2: stage B(t+2) h0; MFMA Q11(ahi,b1); publish t+1 ----
        stage(B, Bbuf, col0, t2, 0);
        __builtin_amdgcn_s_setprio(1);
#pragma unroll
        for (int m2 = 0; m2 < 4; ++m2)
#pragma unroll
            for (int n2 = 0; n2 < 2; ++n2)
#pragma unroll
                for (int ks = 0; ks < 2; ++ks)
                    acc[4 + m2][2 + n2] = __builtin_amdgcn_mfma_f32_16x16x32_bf16(
                        ahi[m2][ks], b1[n2][ks], acc[4 + m2][2 + n2], 0, 0, 0);
        __builtin_amdgcn_s_setprio(0);
        // publish: tile t+1 fully landed; 6 newest (A(t+2)x4, B(t+2)h0 x2) fly
        asm volatile("s_waitcnt vmcnt(6)\ns_barrier" ::: "memory");

        // ---- P3: read alo,b0 of t+1; stage B(t+2)h1; MFMA Q10(ahi,b0c) ----
#pragma unroll
        for (int m2 = 0; m2 < 4; ++m2)
#pragma unroll
            for (int ks = 0; ks < 2; ++ks)
                alo[m2][ks] = *(const short8*)(An + aoff + ((m2 * 2 + ks) << 10));
#pragma unroll
        for (int n2 = 0; n2 < 2; ++n2)
#pragma unroll
            for (int ks = 0; ks < 2; ++ks)
                b0n[n2][ks] = *(const short8*)(Bn + boff + ((n2 * 2 + ks) << 10));
        stage(B, Bbuf, col0, t2, 1);
        __builtin_amdgcn_s_setprio(1);
#pragma unroll
        for (int m2 = 0; m2 < 4; ++m2)
#pragma unroll
            for (int n2 = 0; n2 < 2; ++n2)
#pragma unroll
                for (int ks = 0; ks < 2; ++ks)
                    acc[4 + m2][n2] = __builtin_amdgcn_mfma_f32_16x16x32_bf16(
                        ahi[m2][ks], b0c[n2][ks], acc[4 + m2][n2], 0, 0, 0);
        __builtin_amdgcn_s_setprio(0);
    };

#pragma unroll 1
    for (int tt = 0; tt < NT / 2; ++tt) {
        const int t = 2 * tt;
        body(t,     A0, B0, A1, B1, b0A, b0B);
        body(t + 1, A1, B1, A0, B0, b0B, b0A);
    }
    asm volatile("s_waitcnt vmcnt(0)" ::: "memory");

    // ---- epilogue: D col = lane&15, row = (lane>>4)*4 + r ----
#pragma unroll
    for (int mf = 0; mf < 8; ++mf) {
        const int grow0 = row0 + wr * 128 + mf * 16 + ((l >> 4) << 2);
#pragma unroll
        for (int nf = 0; nf < 4; ++nf) {
            const int gcol = col0 + wc * 64 + nf * 16 + (l & 15);
            float bias_v = 0.f;
            if constexpr (EPI == 0 || EPI == 2) {
                bias_v = bias[gcol];
            }
#pragma unroll
            for (int r = 0; r < 4; ++r) {
                const int grow = grow0 + r;
                const size_t idx = (size_t)grow * DIM + gcol;
                const float a = acc[mf][nf][r];
                if constexpr (EPI == 0) {
                    ((unsigned short*)Cout)[idx] = f2bf(a + bias_v);
                } else if constexpr (EPI == 1) {
                    ((unsigned short*)Cout)[idx] = f2bf(__expf(a * 0.015625f));
                } else if constexpr (EPI == 2) {
                    ((float*)Cout)[idx] = a + bias_v + bf2f(resb[idx]);
                } else {
                    ((unsigned short*)Cout)[idx] = f2bf(a * rowscale[grow]);
                }
            }
        }
    }
}

// ---------------------------------------------------------------------------
// Row sum of E (bf16) -> invs[row] = 1/sum. One block (256 thr) per row.
// ---------------------------------------------------------------------------
__global__ __launch_bounds__(256)
void rowsum_kernel(const unsigned short* __restrict__ E, float* __restrict__ invs) {
    const int row = blockIdx.x;
    const int t = threadIdx.x;
    const unsigned short* src = E + (size_t)row * DIM + t * 16;

    float s = 0.f;
#pragma unroll
    for (int j = 0; j < 2; ++j) {
        short8 v = *(const short8*)(src + j * 8);
#pragma unroll
        for (int e = 0; e < 8; ++e)
            s += bf2f((unsigned short)v[e]);
    }
#pragma unroll
    for (int off = 32; off > 0; off >>= 1) s += __shfl_xor(s, off);

    __shared__ float red[4];
    if ((t & 63) == 0) red[t >> 6] = s;
    __syncthreads();
    if (t == 0) {
        const float tot = (red[0] + red[1]) + (red[2] + red[3]);
        invs[row] = 1.0f / tot;
    }
}

// ---------------------------------------------------------------------------
extern "C" void kernel_launch(void* const* d_in, const int* in_sizes, int n_in,
                              void* d_out, int out_size, void* d_ws, size_t ws_size,
                              hipStream_t stream) {
    const float* query = (const float*)d_in[0];
    const float* key   = (const float*)d_in[1];
    const float* value = (const float*)d_in[2];
    const float* Wq    = (const float*)d_in[3];
    const float* bq    = (const float*)d_in[4];
    const float* Wk    = (const float*)d_in[5];
    const float* bk    = (const float*)d_in[6];
    const float* Wv    = (const float*)d_in[7];
    const float* bv    = (const float*)d_in[8];
    const float* Wo    = (const float*)d_in[9];
    const float* bo    = (const float*)d_in[10];

    const size_t SZ = (size_t)DIM * DIM;
    unsigned short* qb   = (unsigned short*)d_ws;
    unsigned short* kb   = qb + SZ;
    unsigned short* vb   = kb + SZ;
    unsigned short* xb   = vb + SZ;          // reused cast buffer (inputs); after the
                                             // v-projection step it holds bf16(value)
                                             // and is NOT overwritten afterwards.
    unsigned short* wb   = xb + SZ;          // reused cast buffer (weights)
    unsigned short* Eb   = wb + SZ;          // E = exp(logits) bf16
    unsigned short* ctxb = Eb + SZ;
    float* invs = (float*)(ctxb + SZ);       // 4096 f32
    // total ws use: 7*SZ*2 + 16KB = 235 MB

    const dim3 cg(16384), cb(256);
    const dim3 gg(256), gb(512);

    // q = query @ Wq.T + bq
    cast_kernel<<<cg, cb, 0, stream>>>(query, xb);
    cast_kernel<<<cg, cb, 0, stream>>>(Wq, wb);
    gemm256<0><<<gg, gb, 0, stream>>>(xb, wb, qb, bq, nullptr, nullptr);
    // k = key @ Wk.T + bk
    cast_kernel<<<cg, cb, 0, stream>>>(key, xb);
    cast_kernel<<<cg, cb, 0, stream>>>(Wk, wb);
    gemm256<0><<<gg, gb, 0, stream>>>(xb, wb, kb, bk, nullptr, nullptr);
    // v = value @ Wv.T + bv   (xb keeps bf16(value) for the final residual)
    cast_kernel<<<cg, cb, 0, stream>>>(value, xb);
    cast_kernel<<<cg, cb, 0, stream>>>(Wv, wb);
    gemm256<0><<<gg, gb, 0, stream>>>(xb, wb, vb, bv, nullptr, nullptr);
    // E = exp((q @ k.T)/64)   (bf16; no max-sub needed, max logit ~9)
    gemm256<1><<<gg, gb, 0, stream>>>(qb, kb, Eb, nullptr, nullptr, nullptr);
    // invs[row] = 1/rowsum(E)
    rowsum_kernel<<<4096, 256, 0, stream>>>(Eb, invs);
    // ctx = softmax(scores) @ v.T = (E @ v.T) * invs[row]
    gemm256<3><<<gg, gb, 0, stream>>>(Eb, vb, ctxb, nullptr, nullptr, invs);
    // out = ctx @ Wo.T + bo + value   (residual = bf16 cast of RAW value, in xb)
    cast_kernel<<<cg, cb, 0, stream>>>(Wo, wb);
    gemm256<2><<<gg, gb, 0, stream>>>(ctxb, wb, d_out, bo, xb, nullptr);
}